// Round 6
// baseline (206.793 us; speedup 1.0000x reference)
//
#include <hip/hip_runtime.h>
#include <hip/hip_bf16.h>

// LowRankAttention: kv = x @ Wkv^T ; S = routers @ kv^T * scale ; P = softmax(S)
// ; AO = P @ kv ; out = AO @ Wproj^T + bias.  All GEMMs bf16 MFMA (f32 accum).
// Shapes: bs=32 ns=512 seq=1024 H=8 d_r=64 d_model=256.

typedef __attribute__((ext_vector_type(8))) short short8;
typedef __attribute__((ext_vector_type(4))) short short4v;
typedef __attribute__((ext_vector_type(4))) float f32x4;
typedef __attribute__((ext_vector_type(4))) unsigned int uint4v;
typedef __attribute__((ext_vector_type(4))) unsigned short ushort4v;

__device__ inline unsigned short f2bf(float f) {
  unsigned int u = __float_as_uint(f);
  u += 0x7FFFu + ((u >> 16) & 1u);   // RNE
  return (unsigned short)(u >> 16);
}

__device__ __forceinline__ void async_copy16(unsigned short* lds, const unsigned short* g) {
  __builtin_amdgcn_global_load_lds(
      (const __attribute__((address_space(1))) unsigned int*)g,
      (__attribute__((address_space(3))) unsigned int*)lds,
      16, 0, 0);
}

__global__ __launch_bounds__(256) void cast_f32_bf16(const float* __restrict__ in,
                                                     unsigned short* __restrict__ out, int n4) {
  int i = blockIdx.x * 256 + threadIdx.x;
  if (i >= n4) return;
  float4 v = ((const float4*)in)[i];
  ushort4v w; w.x = f2bf(v.x); w.y = f2bf(v.y); w.z = f2bf(v.z); w.w = f2bf(v.w);
  ((ushort4v*)out)[i] = w;
}

// ============ 256x256 8-phase GEMM: C[m,n] = sum_k A[m,k]*B[n,k] (both bf16) ============
// 512 threads = 8 waves (2M x 4N); wave tile 128x64; BK=64 split as two k-halves of 32.
// LDS: sA/sB [2 buf][2 khalf][256 rows x 32 cols] bf16 = 128 KiB total. global_load_lds
// width-16 staging, counted vmcnt(6) only at tile boundary.
// Bank-conflict swizzle (both-sides involution): 16B slot s of row r maps to
// s ^ ((r>>1)&3). Source address pre-swizzled (gload_lds dest stays linear);
// ds_reads apply the same XOR (constant per lane). Residual 2-way = free (m136).
__global__ __launch_bounds__(512, 1) void gemm1_8phase(
    const unsigned short* __restrict__ A, const unsigned short* __restrict__ B,
    unsigned short* __restrict__ C, int lda, int ldb, int ldc, int K, int nWGn)
{
  __shared__ __align__(16) unsigned short sA[2][2][8192];
  __shared__ __align__(16) unsigned short sB[2][2][8192];

  const int tid = threadIdx.x;
  const int cpx = gridDim.x >> 3;
  const int swz = (blockIdx.x & 7) * cpx + (blockIdx.x >> 3);
  const int bn = swz % nWGn, bm = swz / nWGn;

  const int wave = tid >> 6, lane = tid & 63;
  const int wm = wave >> 2, wn = wave & 3;
  const int lr = lane & 15, ls = lane >> 4;
  const int lsw8 = (ls ^ ((lr >> 1) & 3)) * 8;   // swizzled read slot (shorts)

  const int r0 = tid >> 2;
  const int sl0 = (tid & 3) ^ ((tid >> 3) & 3);  // (tid>>3)&3 == (r0>>1)&3; row+128 identical
  const unsigned short* gA = A + (long long)(bm * 256 + r0) * lda + sl0 * 8;
  const unsigned short* gB = B + (long long)(bn * 256 + r0) * ldb + sl0 * 8;
  const long long lda128 = (long long)128 * lda, ldb128 = (long long)128 * ldb;

#define STA(b_, k_, t_) { const unsigned short* g_ = gA + (t_) * 64 + (k_) * 32; \
    async_copy16(&sA[b_][k_][tid * 8], g_); \
    async_copy16(&sA[b_][k_][4096 + tid * 8], g_ + lda128); }
#define STB(b_, k_, t_) { const unsigned short* g_ = gB + (t_) * 64 + (k_) * 32; \
    async_copy16(&sB[b_][k_][tid * 8], g_); \
    async_copy16(&sB[b_][k_][4096 + tid * 8], g_ + ldb128); }

  f32x4 acc[8][4];
  #pragma unroll
  for (int mi = 0; mi < 8; ++mi)
    #pragma unroll
    for (int ni = 0; ni < 4; ++ni)
      acc[mi][ni] = f32x4{0.f, 0.f, 0.f, 0.f};

  const int KT = K >> 6;
  STB(0, 0, 0) STA(0, 0, 0) STB(0, 1, 0) STA(0, 1, 0)
  if (KT > 1) {
    STB(1, 0, 1) STA(1, 0, 1) STB(1, 1, 1)
    asm volatile("s_waitcnt vmcnt(6)" ::: "memory");
  } else {
    asm volatile("s_waitcnt vmcnt(0)" ::: "memory");
  }
  __builtin_amdgcn_s_barrier();
  __builtin_amdgcn_sched_barrier(0);

  for (int t = 0; t < KT; ++t) {
    const int b = t & 1, nb = b ^ 1;
    const bool hasT1 = (t + 1) < KT, hasT2 = (t + 2) < KT;
    short8 af[4], bf[4];

    // ---- P1: (mh=0, kk=0) ----
    #pragma unroll
    for (int mi = 0; mi < 4; ++mi)
      af[mi] = *(const short8*)&sA[b][0][(wm * 128 + mi * 16 + lr) * 32 + lsw8];
    #pragma unroll
    for (int ni = 0; ni < 4; ++ni)
      bf[ni] = *(const short8*)&sB[b][0][(wn * 64 + ni * 16 + lr) * 32 + lsw8];
    if (hasT1) { STA(nb, 1, t + 1) }
    __builtin_amdgcn_s_barrier();
    __builtin_amdgcn_s_setprio(1);
    #pragma unroll
    for (int mi = 0; mi < 4; ++mi)
      #pragma unroll
      for (int ni = 0; ni < 4; ++ni)
        acc[mi][ni] = __builtin_amdgcn_mfma_f32_16x16x32_bf16(af[mi], bf[ni], acc[mi][ni], 0, 0, 0);
    __builtin_amdgcn_s_setprio(0);
    __builtin_amdgcn_s_barrier();

    // ---- P2: (mh=1, kk=0), B-frags held in regs ----
    #pragma unroll
    for (int mi = 0; mi < 4; ++mi)
      af[mi] = *(const short8*)&sA[b][0][(wm * 128 + (4 + mi) * 16 + lr) * 32 + lsw8];
    if (hasT2) { STB(b, 0, t + 2) }
    __builtin_amdgcn_s_barrier();
    __builtin_amdgcn_s_setprio(1);
    #pragma unroll
    for (int mi = 0; mi < 4; ++mi)
      #pragma unroll
      for (int ni = 0; ni < 4; ++ni)
        acc[4 + mi][ni] = __builtin_amdgcn_mfma_f32_16x16x32_bf16(af[mi], bf[ni], acc[4 + mi][ni], 0, 0, 0);
    __builtin_amdgcn_s_setprio(0);
    __builtin_amdgcn_s_barrier();

    // ---- P3: (mh=0, kk=1) ----
    #pragma unroll
    for (int mi = 0; mi < 4; ++mi)
      af[mi] = *(const short8*)&sA[b][1][(wm * 128 + mi * 16 + lr) * 32 + lsw8];
    #pragma unroll
    for (int ni = 0; ni < 4; ++ni)
      bf[ni] = *(const short8*)&sB[b][1][(wn * 64 + ni * 16 + lr) * 32 + lsw8];
    if (hasT2) { STA(b, 0, t + 2) }
    __builtin_amdgcn_s_barrier();
    __builtin_amdgcn_s_setprio(1);
    #pragma unroll
    for (int mi = 0; mi < 4; ++mi)
      #pragma unroll
      for (int ni = 0; ni < 4; ++ni)
        acc[mi][ni] = __builtin_amdgcn_mfma_f32_16x16x32_bf16(af[mi], bf[ni], acc[mi][ni], 0, 0, 0);
    __builtin_amdgcn_s_setprio(0);
    __builtin_amdgcn_s_barrier();

    // ---- P4: (mh=1, kk=1) ----
    #pragma unroll
    for (int mi = 0; mi < 4; ++mi)
      af[mi] = *(const short8*)&sA[b][1][(wm * 128 + (4 + mi) * 16 + lr) * 32 + lsw8];
    if (hasT2) { STB(b, 1, t + 2) }
    __builtin_amdgcn_s_barrier();
    __builtin_amdgcn_s_setprio(1);
    #pragma unroll
    for (int mi = 0; mi < 4; ++mi)
      #pragma unroll
      for (int ni = 0; ni < 4; ++ni)
        acc[4 + mi][ni] = __builtin_amdgcn_mfma_f32_16x16x32_bf16(af[mi], bf[ni], acc[4 + mi][ni], 0, 0, 0);
    __builtin_amdgcn_s_setprio(0);
    if (t == KT - 2) {
      asm volatile("s_waitcnt vmcnt(0)" ::: "memory");
    } else if (t < KT - 2) {
      asm volatile("s_waitcnt vmcnt(6)" ::: "memory");
    }
    __builtin_amdgcn_s_barrier();
    __builtin_amdgcn_sched_barrier(0);
  }
#undef STA
#undef STB

  #pragma unroll
  for (int mi = 0; mi < 8; ++mi) {
    #pragma unroll
    for (int ni = 0; ni < 4; ++ni) {
      int row = bm * 256 + wm * 128 + mi * 16 + ls * 4;
      int col = bn * 256 + wn * 64 + ni * 16 + lr;
      #pragma unroll
      for (int r = 0; r < 4; ++r)
        C[(long long)(row + r) * ldc + col] = f2bf(acc[mi][ni][r]);
    }
  }
}

// ============ fused attention: per (b,h) wg — S = R@kv^T*scale, softmax -> attnw(f32)
// + P(bf16, in-place in LDS), AO = P@kv -> ao_b.  4 waves x 16 router rows. ============
// LDS: S f32 [64][512] (131,072 B; P bf16 packed in place, shorts pitch 1024)
//      kvT bf16 [16][520] (16,640 B) staged per 16-wide d-block.  Total 147,712 B.
__global__ __launch_bounds__(256, 1) void attn_fused(
    const unsigned short* __restrict__ R,   // routers bf16 (8,64,256)
    const unsigned short* __restrict__ kv,  // (16384, 2048): row b*512+n, col h*256+d
    float* __restrict__ attnw,              // (bh, 64, 512) f32
    unsigned short* __restrict__ ao)        // (2048, 2048): row b*64+r, col h*256+d
{
  __shared__ __align__(16) float S_lds[64 * 512];
  __shared__ __align__(16) unsigned short kvT[16 * 520];

  const int bh = blockIdx.x;
  const int b = bh >> 3, h = bh & 7;
  const int tid = threadIdx.x;
  const int wave = tid >> 6, lane = tid & 63;
  const int lr = lane & 15, ls = lane >> 4;
  const int r0 = wave * 16;

  const unsigned short* kvb = kv + (long long)b * 512 * 2048 + h * 256;

  // ---- score: S[r][n] = sum_d R[h][r][d] * kv[b,h][n][d] * 1/16 ----
  short8 af[8];
  #pragma unroll
  for (int kk = 0; kk < 8; ++kk)
    af[kk] = *(const short8*)&R[h * 16384 + (r0 + lr) * 256 + kk * 32 + ls * 8];

  for (int nt = 0; nt < 32; nt += 2) {
    short8 bf0[8], bf1[8];
    #pragma unroll
    for (int kk = 0; kk < 8; ++kk) {
      bf0[kk] = *(const short8*)&kvb[(long long)(nt * 16 + lr) * 2048 + kk * 32 + ls * 8];
      bf1[kk] = *(const short8*)&kvb[(long long)(nt * 16 + 16 + lr) * 2048 + kk * 32 + ls * 8];
    }
    f32x4 a0 = f32x4{0.f, 0.f, 0.f, 0.f}, a1 = f32x4{0.f, 0.f, 0.f, 0.f};
    #pragma unroll
    for (int kk = 0; kk < 8; ++kk) {
      a0 = __builtin_amdgcn_mfma_f32_16x16x32_bf16(af[kk], bf0[kk], a0, 0, 0, 0);
      a1 = __builtin_amdgcn_mfma_f32_16x16x32_bf16(af[kk], bf1[kk], a1, 0, 0, 0);
    }
    #pragma unroll
    for (int j = 0; j < 4; ++j) {
      S_lds[(r0 + ls * 4 + j) * 512 + nt * 16 + lr]        = a0[j] * 0.0625f;
      S_lds[(r0 + ls * 4 + j) * 512 + (nt + 1) * 16 + lr]  = a1[j] * 0.0625f;
    }
  }

  // ---- softmax per wave over its 16 rows; write attnw f32 + P bf16 in place ----
  unsigned short* Ps = (unsigned short*)S_lds;  // P row r at shorts r*1024
  for (int r = 0; r < 16; ++r) {
    const int row = r0 + r;
    float* rp = &S_lds[row * 512 + lane * 8];
    float4 va = *(const float4*)rp;
    float4 vb = *(const float4*)(rp + 4);
    float v[8] = {va.x, va.y, va.z, va.w, vb.x, vb.y, vb.z, vb.w};
    float m = v[0];
    #pragma unroll
    for (int i = 1; i < 8; ++i) m = fmaxf(m, v[i]);
    #pragma unroll
    for (int d = 1; d < 64; d <<= 1) m = fmaxf(m, __shfl_xor(m, d, 64));
    float s = 0.f;
    #pragma unroll
    for (int i = 0; i < 8; ++i) { v[i] = __expf(v[i] - m); s += v[i]; }
    #pragma unroll
    for (int d = 1; d < 64; d <<= 1) s += __shfl_xor(s, d, 64);
    float inv = 1.0f / s;
    #pragma unroll
    for (int i = 0; i < 8; ++i) v[i] *= inv;
    float* gw = attnw + (long long)bh * 32768 + row * 512 + lane * 8;
    *(float4*)gw       = float4{v[0], v[1], v[2], v[3]};
    *(float4*)(gw + 4) = float4{v[4], v[5], v[6], v[7]};
    ushort4v w0, w1;
    w0.x = f2bf(v[0]); w0.y = f2bf(v[1]); w0.z = f2bf(v[2]); w0.w = f2bf(v[3]);
    w1.x = f2bf(v[4]); w1.y = f2bf(v[5]); w1.z = f2bf(v[6]); w1.w = f2bf(v[7]);
    unsigned short* pp = &Ps[row * 1024 + lane * 8];
    *(ushort4v*)pp       = w0;
    *(ushort4v*)(pp + 4) = w1;
  }

  // ---- PV: AO[r][d] = sum_n P[r][n] * kv[n][d], 16 d-blocks of 16 ----
  short8 pf[16];
  #pragma unroll
  for (int kc = 0; kc < 16; ++kc)
    pf[kc] = *(const short8*)&Ps[(r0 + lr) * 1024 + kc * 32 + ls * 8];

  for (int d0 = 0; d0 < 256; d0 += 16) {
    // stage kvT[d - d0][n] = kv[n][d]: thread t covers n in {t, t+256}, dg in {0,1}
    #pragma unroll
    for (int i = 0; i < 2; ++i) {
      int n = i * 256 + tid;
      #pragma unroll
      for (int dg = 0; dg < 2; ++dg) {
        uint4v v = *(const uint4v*)&kvb[(long long)n * 2048 + d0 + dg * 8];
        const unsigned short* pv = (const unsigned short*)&v;
        #pragma unroll
        for (int q = 0; q < 8; ++q) kvT[(dg * 8 + q) * 520 + n] = pv[q];
      }
    }
    __syncthreads();
    f32x4 c0 = f32x4{0.f, 0.f, 0.f, 0.f};
    #pragma unroll
    for (int kc = 0; kc < 16; ++kc) {
      short8 b0 = *(const short8*)&kvT[lr * 520 + kc * 32 + ls * 8];
      c0 = __builtin_amdgcn_mfma_f32_16x16x32_bf16(pf[kc], b0, c0, 0, 0, 0);
    }
    #pragma unroll
    for (int q = 0; q < 4; ++q) {
      int r = r0 + ls * 4 + q;
      ao[(long long)(b * 64 + r) * 2048 + h * 256 + d0 + lr] = f2bf(c0[q]);
    }
    __syncthreads();
  }
}

// ---------------- reg-staged GEMM (proj) ----------
template<int BM,int BN,int BK,int WM,int WN,bool TRANS_B,bool A_F32,bool OUT_BF16,bool DO_SCALE,bool DO_BIAS>
__global__ __launch_bounds__(256) void gemm_bt(
    const void* __restrict__ Av, const unsigned short* __restrict__ Bp,
    void* __restrict__ Cv, const float* __restrict__ bias,
    int lda, int ldb, int ldc, int K, int nWGn,
    long long strAo, long long strAi, long long strBo, long long strBi,
    long long strCo, long long strCi, int binner, float scale)
{
  constexpr int PADA = 8;
  constexpr int PADB = TRANS_B ? 4 : 8;
  constexpr int STRA = BK + PADA;
  constexpr int STRB = BK + PADB;
  constexpr int NWN = BN / WN;
  constexpr int MF = WM / 16, NF = WN / 16;
  __shared__ __align__(16) unsigned short lds_a[BM * STRA];
  __shared__ __align__(16) unsigned short lds_b[BN * STRB];

  const int tid = threadIdx.x;
  const int bn = blockIdx.x % nWGn;
  const int bm = blockIdx.x / nWGn;
  const int batch = blockIdx.y;
  const int bo = batch / binner, bi = batch % binner;

  const int wave = tid >> 6, lane = tid & 63;
  const int wm = wave / NWN, wn = wave % NWN;
  const int lr = lane & 15;
  const int lk = (lane >> 4) * 8;

  const long long abase = bo*strAo + bi*strAi + (long long)bm*BM*lda;
  const long long bbase = bo*strBo + bi*strBi;

  f32x4 acc[MF][NF];
  #pragma unroll
  for (int mi = 0; mi < MF; ++mi)
    #pragma unroll
    for (int ni = 0; ni < NF; ++ni)
      acc[mi][ni] = f32x4{0.f, 0.f, 0.f, 0.f};

  for (int k0 = 0; k0 < K; k0 += BK) {
    if constexpr (A_F32) {
      const float* Af = (const float*)Av + abase + k0;
      #pragma unroll
      for (int i = 0; i < BM*BK/1024; ++i) {
        int c = i*256 + tid;
        int r = c / (BK/4);
        int kc = (c % (BK/4)) * 4;
        float4 v = *(const float4*)(Af + (long long)r*lda + kc);
        ushort4v w; w.x=f2bf(v.x); w.y=f2bf(v.y); w.z=f2bf(v.z); w.w=f2bf(v.w);
        *(ushort4v*)&lds_a[r*STRA + kc] = w;
      }
    } else {
      const unsigned short* Ab2 = (const unsigned short*)Av + abase + k0;
      #pragma unroll
      for (int i = 0; i < BM*BK/2048; ++i) {
        int c = i*256 + tid;
        int r = c / (BK/8);
        int kc = (c % (BK/8)) * 8;
        *(uint4v*)&lds_a[r*STRA + kc] = *(const uint4v*)(Ab2 + (long long)r*lda + kc);
      }
    }
    if constexpr (!TRANS_B) {
      const unsigned short* Bb2 = Bp + bbase + (long long)bn*BN*ldb + k0;
      #pragma unroll
      for (int i = 0; i < BN*BK/2048; ++i) {
        int c = i*256 + tid;
        int r = c / (BK/8);
        int kc = (c % (BK/8)) * 8;
        *(uint4v*)&lds_b[r*STRB + kc] = *(const uint4v*)(Bb2 + (long long)r*ldb + kc);
      }
    } else {
      const unsigned short* Bb2 = Bp + bbase + (long long)k0*ldb + (long long)bn*BN;
      #pragma unroll
      for (int i = 0; i < BN*BK/2048; ++i) {
        int c = i*256 + tid;
        int kr = c / (BN/8);
        int nc = (c % (BN/8)) * 8;
        uint4v v = *(const uint4v*)(Bb2 + (long long)kr*ldb + nc);
        const unsigned short* pv = (const unsigned short*)&v;
        #pragma unroll
        for (int j = 0; j < 8; ++j) lds_b[(nc+j)*STRB + kr] = pv[j];
      }
    }
    __syncthreads();

    #pragma unroll
    for (int kk = 0; kk < BK/32; ++kk) {
      short8 af[MF]; short8 bfr[NF];
      #pragma unroll
      for (int mi = 0; mi < MF; ++mi)
        af[mi] = *(const short8*)&lds_a[(wm*WM + mi*16 + lr)*STRA + kk*32 + lk];
      #pragma unroll
      for (int ni = 0; ni < NF; ++ni) {
        if constexpr (TRANS_B) {
          int base = (wn*WN + ni*16 + lr)*STRB + kk*32 + lk;
          short4v lo = *(const short4v*)&lds_b[base];
          short4v hi = *(const short4v*)&lds_b[base + 4];
          short8 t; t[0]=lo[0]; t[1]=lo[1]; t[2]=lo[2]; t[3]=lo[3];
                    t[4]=hi[0]; t[5]=hi[1]; t[6]=hi[2]; t[7]=hi[3];
          bfr[ni] = t;
        } else {
          bfr[ni] = *(const short8*)&lds_b[(wn*WN + ni*16 + lr)*STRB + kk*32 + lk];
        }
      }
      #pragma unroll
      for (int mi = 0; mi < MF; ++mi)
        #pragma unroll
        for (int ni = 0; ni < NF; ++ni)
          acc[mi][ni] = __builtin_amdgcn_mfma_f32_16x16x32_bf16(af[mi], bfr[ni], acc[mi][ni], 0, 0, 0);
    }
    __syncthreads();
  }

  const long long cbase = bo*strCo + bi*strCi;
  const int cr0 = (lane >> 4) * 4;
  #pragma unroll
  for (int mi = 0; mi < MF; ++mi) {
    #pragma unroll
    for (int ni = 0; ni < NF; ++ni) {
      int row = bm*BM + wm*WM + mi*16 + cr0;
      int col = bn*BN + wn*WN + ni*16 + lr;
      float badd = DO_BIAS ? bias[col] : 0.f;
      #pragma unroll
      for (int r = 0; r < 4; ++r) {
        float x = acc[mi][ni][r];
        if constexpr (DO_SCALE) x *= scale;
        x += badd;
        long long addr = cbase + (long long)(row + r)*ldc + col;
        if constexpr (OUT_BF16) ((unsigned short*)Cv)[addr] = f2bf(x);
        else                    ((float*)Cv)[addr] = x;
      }
    }
  }
}

extern "C" void kernel_launch(void* const* d_in, const int* in_sizes, int n_in,
                              void* d_out, int out_size, void* d_ws, size_t ws_size,
                              hipStream_t stream) {
  const float* x       = (const float*)d_in[0];   // (32,512,1024)
  const float* routers = (const float*)d_in[1];   // (8,64,256)
  const float* wkv     = (const float*)d_in[2];   // (2048,1024)
  const float* projw   = (const float*)d_in[3];   // (1024,2048)
  const float* pbias   = (const float*)d_in[4];   // (1024,)

  char* ws = (char*)d_ws;
  unsigned short* wkv_b   = (unsigned short*)(ws);                //  4,194,304 B
  unsigned short* projw_b = (unsigned short*)(ws +  4194304);     //  4,194,304 B
  unsigned short* kv_b    = (unsigned short*)(ws +  8388608);     // 67,108,864 B (16384 x 2048)
  // region R: xb lives here ONLY during GEMM1; afterwards routers_b; ao_b separate.
  unsigned short* xb        = (unsigned short*)(ws + 75497472);   // 33,554,432 B (16384 x 1024)
  unsigned short* routers_b = (unsigned short*)(ws + 75497472);   //    262,144 B
  unsigned short* ao_b      = (unsigned short*)(ws + 92536832);   //  8,388,608 B (2048 x 2048)

  float* out0  = (float*)d_out;            // (32,64,1024)
  float* attnw = out0 + 2097152;           // (32,8,64,512) f32 softmax output

  cast_f32_bf16<<<2048,  256, 0, stream>>>(wkv,   wkv_b,   524288);
  cast_f32_bf16<<<2048,  256, 0, stream>>>(projw, projw_b, 524288);
  cast_f32_bf16<<<16384, 256, 0, stream>>>(x,     xb,      4194304);

  // kv = x @ wkv^T : M=16384 N=2048 K=1024 -> bf16 kv_b ; grid 64x8 = 512 wgs
  gemm1_8phase<<<512, 512, 0, stream>>>(xb, wkv_b, kv_b, 1024, 1024, 2048, 1024, 8);

  cast_f32_bf16<<<128, 256, 0, stream>>>(routers, routers_b, 32768);

  // fused score+softmax+PV : one wg per (b,h)
  attn_fused<<<256, 256, 0, stream>>>(routers_b, kv_b, attnw, ao_b);

  // out = AO @ projw^T + bias : M=2048 N=1024 K=2048, out f32
  gemm_bt<64,128,64,64,32,false,false,false,false,true><<<dim3(256,1), 256, 0, stream>>>(
      ao_b, projw_b, out0, pbias, 2048, 2048, 1024, 2048, 8,
      0,0, 0,0, 0,0, 1, 1.0f);
}

// Round 7
// 184.250 us; speedup vs baseline: 1.1224x; 1.1224x over previous
//
#include <hip/hip_runtime.h>
#include <hip/hip_bf16.h>

// LowRankAttention: kv = x @ Wkv^T ; S = routers @ kv^T * scale ; P = softmax(S)
// ; AO = P @ kv ; out = AO @ Wproj^T + bias.  All GEMMs bf16 MFMA (f32 accum).
// Shapes: bs=32 ns=512 seq=1024 H=8 d_r=64 d_model=256.

typedef __attribute__((ext_vector_type(8))) short short8;
typedef __attribute__((ext_vector_type(4))) short short4v;
typedef __attribute__((ext_vector_type(4))) float f32x4;
typedef __attribute__((ext_vector_type(4))) unsigned int uint4v;
typedef __attribute__((ext_vector_type(4))) unsigned short ushort4v;

__device__ inline unsigned short f2bf(float f) {
  unsigned int u = __float_as_uint(f);
  u += 0x7FFFu + ((u >> 16) & 1u);   // RNE
  return (unsigned short)(u >> 16);
}

__device__ __forceinline__ void async_copy16(unsigned short* lds, const unsigned short* g) {
  __builtin_amdgcn_global_load_lds(
      (const __attribute__((address_space(1))) unsigned int*)g,
      (__attribute__((address_space(3))) unsigned int*)lds,
      16, 0, 0);
}

__global__ __launch_bounds__(256) void cast_f32_bf16(const float* __restrict__ in,
                                                     unsigned short* __restrict__ out, int n4) {
  int i = blockIdx.x * 256 + threadIdx.x;
  if (i >= n4) return;
  float4 v = ((const float4*)in)[i];
  ushort4v w; w.x = f2bf(v.x); w.y = f2bf(v.y); w.z = f2bf(v.z); w.w = f2bf(v.w);
  ((ushort4v*)out)[i] = w;
}

// ============ 256x256 8-phase GEMM: C[m,n] = sum_k A[m,k]*B[n,k] (both bf16) ============
// 512 threads = 8 waves (2M x 4N); wave tile 128x64; BK=64 split as two k-halves of 32.
// LDS: sA/sB [2 buf][2 khalf][256 x 32] bf16 = 128 KiB. gload_lds width-16 staging.
// ONE barrier per phase ([reads; stage; MFMA; bar]) — region-retirement ledger:
//   stage@P1 targets A1(other buf): retired (t-1).P4, ≥1 barrier ago ✓
//   stage@P2 targets B0(cur buf):   retired t.P1  — BAR_P1 separates ✓
//   stage@P3 targets A0(cur buf):   retired t.P2  — BAR_P2 separates ✓
//   stage@P4 targets B1(cur buf):   retired t.P3  — BAR_P3 separates ✓
// Tile-end: per-wave vmcnt(6) THEN barrier => all waves' loads issued through t.P1
// have landed before any t+1.P1 read. Swizzle: slot s of row r -> s ^ ((r>>1)&3),
// pre-swizzled global source + same XOR on ds_read (bank-conflict-free, measured 0).
__global__ __launch_bounds__(512, 1) void gemm1_8phase(
    const unsigned short* __restrict__ A, const unsigned short* __restrict__ B,
    unsigned short* __restrict__ C, int lda, int ldb, int ldc, int K, int nWGn)
{
  __shared__ __align__(16) unsigned short sA[2][2][8192];
  __shared__ __align__(16) unsigned short sB[2][2][8192];

  const int tid = threadIdx.x;
  const int cpx = gridDim.x >> 3;
  const int swz = (blockIdx.x & 7) * cpx + (blockIdx.x >> 3);
  const int bn = swz % nWGn, bm = swz / nWGn;

  const int wave = tid >> 6, lane = tid & 63;
  const int wm = wave >> 2, wn = wave & 3;
  const int lr = lane & 15, ls = lane >> 4;
  const int lsw8 = (ls ^ ((lr >> 1) & 3)) * 8;   // swizzled read slot (shorts)

  const int r0 = tid >> 2;
  const int sl0 = (tid & 3) ^ ((tid >> 3) & 3);  // (tid>>3)&3 == (r0>>1)&3; row+128 identical
  const unsigned short* gA = A + (long long)(bm * 256 + r0) * lda + sl0 * 8;
  const unsigned short* gB = B + (long long)(bn * 256 + r0) * ldb + sl0 * 8;
  const long long lda128 = (long long)128 * lda, ldb128 = (long long)128 * ldb;

#define STA(b_, k_, t_) { const unsigned short* g_ = gA + (t_) * 64 + (k_) * 32; \
    async_copy16(&sA[b_][k_][tid * 8], g_); \
    async_copy16(&sA[b_][k_][4096 + tid * 8], g_ + lda128); }
#define STB(b_, k_, t_) { const unsigned short* g_ = gB + (t_) * 64 + (k_) * 32; \
    async_copy16(&sB[b_][k_][tid * 8], g_); \
    async_copy16(&sB[b_][k_][4096 + tid * 8], g_ + ldb128); }

  f32x4 acc[8][4];
  #pragma unroll
  for (int mi = 0; mi < 8; ++mi)
    #pragma unroll
    for (int ni = 0; ni < 4; ++ni)
      acc[mi][ni] = f32x4{0.f, 0.f, 0.f, 0.f};

  const int KT = K >> 6;
  STB(0, 0, 0) STA(0, 0, 0) STB(0, 1, 0) STA(0, 1, 0)
  if (KT > 1) {
    STB(1, 0, 1) STA(1, 0, 1) STB(1, 1, 1)
    asm volatile("s_waitcnt vmcnt(6)" ::: "memory");
  } else {
    asm volatile("s_waitcnt vmcnt(0)" ::: "memory");
  }
  __builtin_amdgcn_s_barrier();
  __builtin_amdgcn_sched_barrier(0);

  for (int t = 0; t < KT; ++t) {
    const int b = t & 1, nb = b ^ 1;
    const bool hasT1 = (t + 1) < KT, hasT2 = (t + 2) < KT;
    short8 af[4], bf[4];

    // ---- P1: (mh=0, kk=0) ----
    #pragma unroll
    for (int mi = 0; mi < 4; ++mi)
      af[mi] = *(const short8*)&sA[b][0][(wm * 128 + mi * 16 + lr) * 32 + lsw8];
    #pragma unroll
    for (int ni = 0; ni < 4; ++ni)
      bf[ni] = *(const short8*)&sB[b][0][(wn * 64 + ni * 16 + lr) * 32 + lsw8];
    if (hasT1) { STA(nb, 1, t + 1) }
    __builtin_amdgcn_s_setprio(1);
    #pragma unroll
    for (int mi = 0; mi < 4; ++mi)
      #pragma unroll
      for (int ni = 0; ni < 4; ++ni)
        acc[mi][ni] = __builtin_amdgcn_mfma_f32_16x16x32_bf16(af[mi], bf[ni], acc[mi][ni], 0, 0, 0);
    __builtin_amdgcn_s_setprio(0);
    __builtin_amdgcn_s_barrier();

    // ---- P2: (mh=1, kk=0), B-frags held in regs ----
    #pragma unroll
    for (int mi = 0; mi < 4; ++mi)
      af[mi] = *(const short8*)&sA[b][0][(wm * 128 + (4 + mi) * 16 + lr) * 32 + lsw8];
    if (hasT2) { STB(b, 0, t + 2) }
    __builtin_amdgcn_s_setprio(1);
    #pragma unroll
    for (int mi = 0; mi < 4; ++mi)
      #pragma unroll
      for (int ni = 0; ni < 4; ++ni)
        acc[4 + mi][ni] = __builtin_amdgcn_mfma_f32_16x16x32_bf16(af[mi], bf[ni], acc[4 + mi][ni], 0, 0, 0);
    __builtin_amdgcn_s_setprio(0);
    __builtin_amdgcn_s_barrier();

    // ---- P3: (mh=0, kk=1) ----
    #pragma unroll
    for (int mi = 0; mi < 4; ++mi)
      af[mi] = *(const short8*)&sA[b][1][(wm * 128 + mi * 16 + lr) * 32 + lsw8];
    #pragma unroll
    for (int ni = 0; ni < 4; ++ni)
      bf[ni] = *(const short8*)&sB[b][1][(wn * 64 + ni * 16 + lr) * 32 + lsw8];
    if (hasT2) { STA(b, 0, t + 2) }
    __builtin_amdgcn_s_setprio(1);
    #pragma unroll
    for (int mi = 0; mi < 4; ++mi)
      #pragma unroll
      for (int ni = 0; ni < 4; ++ni)
        acc[mi][ni] = __builtin_amdgcn_mfma_f32_16x16x32_bf16(af[mi], bf[ni], acc[mi][ni], 0, 0, 0);
    __builtin_amdgcn_s_setprio(0);
    __builtin_amdgcn_s_barrier();

    // ---- P4: (mh=1, kk=1) ----
    #pragma unroll
    for (int mi = 0; mi < 4; ++mi)
      af[mi] = *(const short8*)&sA[b][1][(wm * 128 + (4 + mi) * 16 + lr) * 32 + lsw8];
    if (hasT2) { STB(b, 1, t + 2) }
    __builtin_amdgcn_s_setprio(1);
    #pragma unroll
    for (int mi = 0; mi < 4; ++mi)
      #pragma unroll
      for (int ni = 0; ni < 4; ++ni)
        acc[4 + mi][ni] = __builtin_amdgcn_mfma_f32_16x16x32_bf16(af[mi], bf[ni], acc[4 + mi][ni], 0, 0, 0);
    __builtin_amdgcn_s_setprio(0);
    if (t == KT - 2) {
      asm volatile("s_waitcnt vmcnt(0)" ::: "memory");
    } else if (t < KT - 2) {
      asm volatile("s_waitcnt vmcnt(6)" ::: "memory");
    }
    __builtin_amdgcn_s_barrier();
    __builtin_amdgcn_sched_barrier(0);
  }
#undef STA
#undef STB

  #pragma unroll
  for (int mi = 0; mi < 8; ++mi) {
    #pragma unroll
    for (int ni = 0; ni < 4; ++ni) {
      int row = bm * 256 + wm * 128 + mi * 16 + ls * 4;
      int col = bn * 256 + wn * 64 + ni * 16 + lr;
      #pragma unroll
      for (int r = 0; r < 4; ++r)
        C[(long long)(row + r) * ldc + col] = f2bf(acc[mi][ni][r]);
    }
  }
}

// ---------------- reg-staged batched GEMM (score, PV, proj) ----------
template<int BM,int BN,int BK,int WM,int WN,bool TRANS_B,bool A_F32,bool OUT_BF16,bool DO_SCALE,bool DO_BIAS>
__global__ __launch_bounds__(256) void gemm_bt(
    const void* __restrict__ Av, const unsigned short* __restrict__ Bp,
    void* __restrict__ Cv, const float* __restrict__ bias,
    int lda, int ldb, int ldc, int K, int nWGn,
    long long strAo, long long strAi, long long strBo, long long strBi,
    long long strCo, long long strCi, int binner, float scale)
{
  constexpr int PADA = 8;
  constexpr int PADB = TRANS_B ? 4 : 8;
  constexpr int STRA = BK + PADA;
  constexpr int STRB = BK + PADB;
  constexpr int NWN = BN / WN;
  constexpr int MF = WM / 16, NF = WN / 16;
  __shared__ __align__(16) unsigned short lds_a[BM * STRA];
  __shared__ __align__(16) unsigned short lds_b[BN * STRB];

  const int tid = threadIdx.x;
  const int bn = blockIdx.x % nWGn;
  const int bm = blockIdx.x / nWGn;
  const int batch = blockIdx.y;
  const int bo = batch / binner, bi = batch % binner;

  const int wave = tid >> 6, lane = tid & 63;
  const int wm = wave / NWN, wn = wave % NWN;
  const int lr = lane & 15;
  const int lk = (lane >> 4) * 8;

  const long long abase = bo*strAo + bi*strAi + (long long)bm*BM*lda;
  const long long bbase = bo*strBo + bi*strBi;

  f32x4 acc[MF][NF];
  #pragma unroll
  for (int mi = 0; mi < MF; ++mi)
    #pragma unroll
    for (int ni = 0; ni < NF; ++ni)
      acc[mi][ni] = f32x4{0.f, 0.f, 0.f, 0.f};

  for (int k0 = 0; k0 < K; k0 += BK) {
    if constexpr (A_F32) {
      const float* Af = (const float*)Av + abase + k0;
      #pragma unroll
      for (int i = 0; i < BM*BK/1024; ++i) {
        int c = i*256 + tid;
        int r = c / (BK/4);
        int kc = (c % (BK/4)) * 4;
        float4 v = *(const float4*)(Af + (long long)r*lda + kc);
        ushort4v w; w.x=f2bf(v.x); w.y=f2bf(v.y); w.z=f2bf(v.z); w.w=f2bf(v.w);
        *(ushort4v*)&lds_a[r*STRA + kc] = w;
      }
    } else {
      const unsigned short* Ab2 = (const unsigned short*)Av + abase + k0;
      #pragma unroll
      for (int i = 0; i < BM*BK/2048; ++i) {
        int c = i*256 + tid;
        int r = c / (BK/8);
        int kc = (c % (BK/8)) * 8;
        *(uint4v*)&lds_a[r*STRA + kc] = *(const uint4v*)(Ab2 + (long long)r*lda + kc);
      }
    }
    if constexpr (!TRANS_B) {
      const unsigned short* Bb2 = Bp + bbase + (long long)bn*BN*ldb + k0;
      #pragma unroll
      for (int i = 0; i < BN*BK/2048; ++i) {
        int c = i*256 + tid;
        int r = c / (BK/8);
        int kc = (c % (BK/8)) * 8;
        *(uint4v*)&lds_b[r*STRB + kc] = *(const uint4v*)(Bb2 + (long long)r*ldb + kc);
      }
    } else {
      const unsigned short* Bb2 = Bp + bbase + (long long)k0*ldb + (long long)bn*BN;
      #pragma unroll
      for (int i = 0; i < BN*BK/2048; ++i) {
        int c = i*256 + tid;
        int kr = c / (BN/8);
        int nc = (c % (BN/8)) * 8;
        uint4v v = *(const uint4v*)(Bb2 + (long long)kr*ldb + nc);
        const unsigned short* pv = (const unsigned short*)&v;
        #pragma unroll
        for (int j = 0; j < 8; ++j) lds_b[(nc+j)*STRB + kr] = pv[j];
      }
    }
    __syncthreads();

    #pragma unroll
    for (int kk = 0; kk < BK/32; ++kk) {
      short8 af[MF]; short8 bfr[NF];
      #pragma unroll
      for (int mi = 0; mi < MF; ++mi)
        af[mi] = *(const short8*)&lds_a[(wm*WM + mi*16 + lr)*STRA + kk*32 + lk];
      #pragma unroll
      for (int ni = 0; ni < NF; ++ni) {
        if constexpr (TRANS_B) {
          int base = (wn*WN + ni*16 + lr)*STRB + kk*32 + lk;
          short4v lo = *(const short4v*)&lds_b[base];
          short4v hi = *(const short4v*)&lds_b[base + 4];
          short8 t; t[0]=lo[0]; t[1]=lo[1]; t[2]=lo[2]; t[3]=lo[3];
                    t[4]=hi[0]; t[5]=hi[1]; t[6]=hi[2]; t[7]=hi[3];
          bfr[ni] = t;
        } else {
          bfr[ni] = *(const short8*)&lds_b[(wn*WN + ni*16 + lr)*STRB + kk*32 + lk];
        }
      }
      #pragma unroll
      for (int mi = 0; mi < MF; ++mi)
        #pragma unroll
        for (int ni = 0; ni < NF; ++ni)
          acc[mi][ni] = __builtin_amdgcn_mfma_f32_16x16x32_bf16(af[mi], bfr[ni], acc[mi][ni], 0, 0, 0);
    }
    __syncthreads();
  }

  const long long cbase = bo*strCo + bi*strCi;
  const int cr0 = (lane >> 4) * 4;
  #pragma unroll
  for (int mi = 0; mi < MF; ++mi) {
    #pragma unroll
    for (int ni = 0; ni < NF; ++ni) {
      int row = bm*BM + wm*WM + mi*16 + cr0;
      int col = bn*BN + wn*WN + ni*16 + lr;
      float badd = DO_BIAS ? bias[col] : 0.f;
      #pragma unroll
      for (int r = 0; r < 4; ++r) {
        float x = acc[mi][ni][r];
        if constexpr (DO_SCALE) x *= scale;
        x += badd;
        long long addr = cbase + (long long)(row + r)*ldc + col;
        if constexpr (OUT_BF16) ((unsigned short*)Cv)[addr] = f2bf(x);
        else                    ((float*)Cv)[addr] = x;
      }
    }
  }
}

// softmax over rows of 512 f32, in place; also emit bf16 copy. 1 wave per row.
__global__ __launch_bounds__(256) void softmax_rows(float* __restrict__ sc,
                                                    unsigned short* __restrict__ P) {
  int row = blockIdx.x * 4 + (threadIdx.x >> 6);
  int lane = threadIdx.x & 63;
  float* rp = sc + (long long)row * 512 + lane * 8;
  float4 a = *(const float4*)rp;
  float4 b = *(const float4*)(rp + 4);
  float v[8] = {a.x, a.y, a.z, a.w, b.x, b.y, b.z, b.w};
  float m = v[0];
  #pragma unroll
  for (int i = 1; i < 8; ++i) m = fmaxf(m, v[i]);
  #pragma unroll
  for (int d = 1; d < 64; d <<= 1) m = fmaxf(m, __shfl_xor(m, d, 64));
  float s = 0.f;
  #pragma unroll
  for (int i = 0; i < 8; ++i) { v[i] = __expf(v[i] - m); s += v[i]; }
  #pragma unroll
  for (int d = 1; d < 64; d <<= 1) s += __shfl_xor(s, d, 64);
  float inv = 1.0f / s;
  #pragma unroll
  for (int i = 0; i < 8; ++i) v[i] *= inv;
  float4 oa = {v[0], v[1], v[2], v[3]}, ob = {v[4], v[5], v[6], v[7]};
  *(float4*)rp = oa; *(float4*)(rp + 4) = ob;
  unsigned short* pp = P + (long long)row * 512 + lane * 8;
  ushort4v w0, w1;
  w0.x=f2bf(v[0]); w0.y=f2bf(v[1]); w0.z=f2bf(v[2]); w0.w=f2bf(v[3]);
  w1.x=f2bf(v[4]); w1.y=f2bf(v[5]); w1.z=f2bf(v[6]); w1.w=f2bf(v[7]);
  *(ushort4v*)pp = w0; *(ushort4v*)(pp + 4) = w1;
}

extern "C" void kernel_launch(void* const* d_in, const int* in_sizes, int n_in,
                              void* d_out, int out_size, void* d_ws, size_t ws_size,
                              hipStream_t stream) {
  const float* x       = (const float*)d_in[0];   // (32,512,1024)
  const float* routers = (const float*)d_in[1];   // (8,64,256)
  const float* wkv     = (const float*)d_in[2];   // (2048,1024)
  const float* projw   = (const float*)d_in[3];   // (1024,2048)
  const float* pbias   = (const float*)d_in[4];   // (1024,)

  char* ws = (char*)d_ws;
  unsigned short* wkv_b   = (unsigned short*)(ws);                //  4,194,304 B
  unsigned short* projw_b = (unsigned short*)(ws +  4194304);     //  4,194,304 B
  unsigned short* kv_b    = (unsigned short*)(ws +  8388608);     // 67,108,864 B (16384 x 2048)
  // region R: xb lives here ONLY during GEMM1; afterwards routers_b + P_b + ao_b.
  unsigned short* xb        = (unsigned short*)(ws + 75497472);   // 33,554,432 B (16384 x 1024)
  unsigned short* routers_b = (unsigned short*)(ws + 75497472);   //    262,144 B
  unsigned short* P_b       = (unsigned short*)(ws + 75759616);   // 16,777,216 B (bh x 64 x 512)
  unsigned short* ao_b      = (unsigned short*)(ws + 92536832);   //  8,388,608 B (2048 x 2048)

  float* out0  = (float*)d_out;            // (32,64,1024)
  float* attnw = out0 + 2097152;           // (32,8,64,512) — f32 scores, softmaxed in place

  cast_f32_bf16<<<2048,  256, 0, stream>>>(wkv,   wkv_b,   524288);
  cast_f32_bf16<<<2048,  256, 0, stream>>>(projw, projw_b, 524288);
  cast_f32_bf16<<<16384, 256, 0, stream>>>(x,     xb,      4194304);

  // kv = x @ wkv^T : M=16384 N=2048 K=1024 -> bf16 kv_b ; grid 64x8 = 512 wgs
  gemm1_8phase<<<512, 512, 0, stream>>>(xb, wkv_b, kv_b, 1024, 1024, 2048, 1024, 8);

  cast_f32_bf16<<<128, 256, 0, stream>>>(routers, routers_b, 32768);

  // S[bh] = routers[h] @ kv[b,h]^T * 1/16 : M=64 N=512 K=256, batch=256, out f32 -> attnw
  gemm_bt<64,128,64,64,32,false,false,false,true,false><<<dim3(4,256), 256, 0, stream>>>(
      routers_b, kv_b, attnw, nullptr, 256, 2048, 512, 256, 4,
      0, 16384, 1048576, 256, 262144, 32768, 8, 0.0625f);

  softmax_rows<<<4096, 256, 0, stream>>>(attnw, P_b);

  // AO[bh] = P[bh] @ kv[b,h] : M=64 N=256 K=512, TRANS_B, out bf16 -> ao_b (b*64+r, h*256+d)
  gemm_bt<64,128,64,64,32,true,false,true,false,false><<<dim3(2,256), 256, 0, stream>>>(
      P_b, kv_b, ao_b, nullptr, 512, 2048, 2048, 512, 2,
      262144, 32768, 1048576, 256, 131072, 256, 8, 1.0f);

  // out = AO @ projw^T + bias : M=2048 N=1024 K=2048, out f32
  gemm_bt<64,128,64,64,32,false,false,false,false,true><<<dim3(256,1), 256, 0, stream>>>(
      ao_b, projw_b, out0, pbias, 2048, 2048, 1024, 2048, 8,
      0,0, 0,0, 0,0, 1, 1.0f);
}